// Round 2
// baseline (87861.536 us; speedup 1.0000x reference)
//
#include <hip/hip_runtime.h>

#define T_STEPS 512
#define BB      256   // batch
#define DD      256   // input dim
#define HH      512   // hidden dim
#define MM      512   // mlp dim
#define AA      64    // action dim

#define NTHR  512
#define GRID  256
#define NGRP  16      // batch groups (16 batches each)
#define GBLK  16      // blocks per group (one per j-chunk)
#define BC    16      // batch rows per group
#define JC    32      // hidden cols per block

#define XHW   768     // 256 (x part) + 512 (h part)
#define XHP   772     // padded LDS row stride (float4-aligned, stride%32==4)

// static device scratch — no reliance on d_ws sizing
__device__ float    g_h[2][BB][HH];
__device__ float    g_hidden[BB][MM];
__device__ unsigned g_cnt[NGRP * 32];   // 128B-padded per group
__device__ unsigned g_gen[NGRP * 32];

__device__ __forceinline__ float sigmoidf_fast(float v) {
    return 1.0f / (1.0f + __expf(-v));
}

// 16-block sense/generation barrier; self-resetting (graph-replay safe)
__device__ __forceinline__ void group_barrier(unsigned* cnt, unsigned* gen) {
    __threadfence();                 // publish this thread's stores at agent scope
    __syncthreads();
    if (threadIdx.x == 0) {
        unsigned my = __hip_atomic_load(gen, __ATOMIC_ACQUIRE, __HIP_MEMORY_SCOPE_AGENT);
        unsigned prev = __hip_atomic_fetch_add(cnt, 1u, __ATOMIC_ACQ_REL, __HIP_MEMORY_SCOPE_AGENT);
        if (prev == GBLK - 1) {
            __hip_atomic_store(cnt, 0u, __ATOMIC_RELAXED, __HIP_MEMORY_SCOPE_AGENT);
            __hip_atomic_fetch_add(gen, 1u, __ATOMIC_RELEASE, __HIP_MEMORY_SCOPE_AGENT);
        } else {
            while (__hip_atomic_load(gen, __ATOMIC_ACQUIRE, __HIP_MEMORY_SCOPE_AGENT) == my) {
                __builtin_amdgcn_s_sleep(1);
            }
        }
    }
    __syncthreads();
}

__global__ __launch_bounds__(NTHR, 2) void policy_gru_kernel(
    const float* __restrict__ x,     // [T, B, D]
    const float* __restrict__ W_ih,  // [3H, D]
    const float* __restrict__ W_hh,  // [3H, H]
    const float* __restrict__ b_ih,  // [3H]
    const float* __restrict__ b_hh,  // [3H]
    const float* __restrict__ W1,    // [M, H]
    const float* __restrict__ b1,    // [M]
    const float* __restrict__ W2,    // [A, M]
    const float* __restrict__ b2,    // [A]
    float* __restrict__ out)         // [B, A]
{
    __shared__ float s_xh[BC * XHP];

    const int tid = threadIdx.x;
    const int blk = blockIdx.x;
    const int g   = blk & 15;        // batch group (same-XCD members: blk%8 equal)
    const int jc  = blk >> 4;        // 0..15
    const int b0  = g * BC;
    const int j0  = jc * JC;
    const int bl  = tid >> 5;        // 0..15
    const int jl  = tid & 31;        // 0..31
    const int b   = b0 + bl;
    const int j   = j0 + jl;

    unsigned* cnt = &g_cnt[g * 32];
    unsigned* gen = &g_gen[g * 32];

    // zero-init h0 for this block's (b,j) slice
    g_h[0][b][j] = 0.0f;

    // loop-invariant per-thread state
    const float bR  = b_ih[j] + b_hh[j];
    const float bZ  = b_ih[HH + j] + b_hh[HH + j];
    const float bXn = b_ih[2 * HH + j];
    const float bHn = b_hh[2 * HH + j];
    const float* __restrict__ wir = W_ih + (size_t)j * DD;
    const float* __restrict__ wiz = W_ih + (size_t)(HH + j) * DD;
    const float* __restrict__ win = W_ih + (size_t)(2 * HH + j) * DD;
    const float* __restrict__ whr = W_hh + (size_t)j * HH;
    const float* __restrict__ whz = W_hh + (size_t)(HH + j) * HH;
    const float* __restrict__ whn = W_hh + (size_t)(2 * HH + j) * HH;

    group_barrier(cnt, gen);

    int cur = 0;
    for (int t = 0; t < T_STEPS; ++t) {
        const float* __restrict__ hcur = &g_h[cur][0][0];
        float* __restrict__ hnxt = &g_h[cur ^ 1][0][0];

        // ---- stage x[t, b0:b0+16, :] ++ hcur[b0:b0+16, :] into LDS ----
        const float* xt = x + ((size_t)t * BB + b0) * DD;
        #pragma unroll
        for (int it = 0; it < 6; ++it) {            // 6*512 = 3072 = 16*(768/4)
            int i   = it * NTHR + tid;
            int row = i / (XHW / 4);
            int c4  = i - row * (XHW / 4);
            float4 v;
            if (c4 < DD / 4) {
                v = *(const float4*)(xt + (size_t)row * DD + c4 * 4);
            } else {
                v = *(const float4*)(hcur + (size_t)(b0 + row) * HH + (c4 * 4 - DD));
            }
            *(float4*)(&s_xh[row * XHP + c4 * 4]) = v;
        }
        __syncthreads();

        // ---- 4 accumulators: r, z, xn, hn over contraction of 768 ----
        float accR = 0.f, accZ = 0.f, accXn = 0.f, accHn = 0.f;
        const float* vrow = s_xh + bl * XHP;
        #pragma unroll 4
        for (int k = 0; k < DD; k += 4) {
            const float4 v  = *(const float4*)(vrow + k);
            const float4 wr = *(const float4*)(wir + k);
            const float4 wz = *(const float4*)(wiz + k);
            const float4 wn = *(const float4*)(win + k);
            accR  += v.x * wr.x + v.y * wr.y + v.z * wr.z + v.w * wr.w;
            accZ  += v.x * wz.x + v.y * wz.y + v.z * wz.z + v.w * wz.w;
            accXn += v.x * wn.x + v.y * wn.y + v.z * wn.z + v.w * wn.w;
        }
        const float* vrh = vrow + DD;
        #pragma unroll 4
        for (int k = 0; k < HH; k += 4) {
            const float4 v  = *(const float4*)(vrh + k);
            const float4 wr = *(const float4*)(whr + k);
            const float4 wz = *(const float4*)(whz + k);
            const float4 wn = *(const float4*)(whn + k);
            accR  += v.x * wr.x + v.y * wr.y + v.z * wr.z + v.w * wr.w;
            accZ  += v.x * wz.x + v.y * wz.y + v.z * wz.z + v.w * wz.w;
            accHn += v.x * wn.x + v.y * wn.y + v.z * wn.z + v.w * wn.w;
        }

        const float r = sigmoidf_fast(accR + bR);
        const float z = sigmoidf_fast(accZ + bZ);
        const float n = tanhf(accXn + bXn + r * (accHn + bHn));
        const float hprev = vrow[DD + j];
        const float hnew  = (1.0f - z) * n + z * hprev;
        hnxt[(size_t)b * HH + j] = hnew;

        group_barrier(cnt, gen);   // only the 16 blocks of this batch-group
        cur ^= 1;
    }

    const float* __restrict__ hfin = &g_h[cur][0][0];

    // ---- MLP layer 1: hidden = tanh(h_final @ W1^T + b1) ----
    {
        const int m = jc * JC + jl;              // this block covers m-chunk jc
        #pragma unroll
        for (int it = 0; it < 4; ++it) {         // 4*512 = 2048 = 16*(512/4)
            int i   = it * NTHR + tid;
            int row = i >> 7;
            int c4  = i & 127;
            *(float4*)(&s_xh[row * XHP + c4 * 4]) =
                *(const float4*)(hfin + (size_t)(b0 + row) * HH + c4 * 4);
        }
        __syncthreads();
        const float* w1r  = W1 + (size_t)m * HH;
        const float* vrow = s_xh + bl * XHP;
        float acc = 0.f;
        #pragma unroll 4
        for (int k = 0; k < HH; k += 4) {
            const float4 v = *(const float4*)(vrow + k);
            const float4 w = *(const float4*)(w1r + k);
            acc += v.x * w.x + v.y * w.y + v.z * w.z + v.w * w.w;
        }
        g_hidden[b][m] = tanhf(acc + b1[m]);
    }

    group_barrier(cnt, gen);

    // ---- MLP layer 2: action = tanh(hidden @ W2^T + b2); block jc==0 per group ----
    if (jc == 0) {
        #pragma unroll
        for (int it = 0; it < 4; ++it) {
            int i   = it * NTHR + tid;
            int row = i >> 7;
            int c4  = i & 127;
            *(float4*)(&s_xh[row * XHP + c4 * 4]) =
                *(const float4*)(&g_hidden[b0 + row][0] + c4 * 4);
        }
        __syncthreads();
        #pragma unroll
        for (int rep = 0; rep < 2; ++rep) {      // 2*512 = 1024 = 16b * 64a
            int idx = rep * NTHR + tid;
            int bl2 = idx >> 6;
            int a   = idx & 63;
            const float* w2r  = W2 + (size_t)a * MM;
            const float* vrow = s_xh + bl2 * XHP;
            float acc = 0.f;
            #pragma unroll 4
            for (int k = 0; k < MM; k += 4) {
                const float4 v = *(const float4*)(vrow + k);
                const float4 w = *(const float4*)(w2r + k);
                acc += v.x * w.x + v.y * w.y + v.z * w.z + v.w * w.w;
            }
            out[(size_t)(b0 + bl2) * AA + a] = tanhf(acc + b2[a]);
        }
    }
}

extern "C" void kernel_launch(void* const* d_in, const int* in_sizes, int n_in,
                              void* d_out, int out_size, void* d_ws, size_t ws_size,
                              hipStream_t stream) {
    (void)in_sizes; (void)n_in; (void)out_size; (void)d_ws; (void)ws_size;
    const float* x    = (const float*)d_in[0];
    const float* W_ih = (const float*)d_in[1];
    const float* W_hh = (const float*)d_in[2];
    const float* b_ih = (const float*)d_in[3];
    const float* b_hh = (const float*)d_in[4];
    const float* W1   = (const float*)d_in[5];
    const float* b1   = (const float*)d_in[6];
    const float* W2   = (const float*)d_in[7];
    const float* b2   = (const float*)d_in[8];
    float* out = (float*)d_out;

    policy_gru_kernel<<<dim3(GRID), dim3(NTHR), 0, stream>>>(
        x, W_ih, W_hh, b_ih, b_hh, W1, b1, W2, b2, out);
}

// Round 3
// 41182.056 us; speedup vs baseline: 2.1335x; 2.1335x over previous
//
#include <hip/hip_runtime.h>

#define T_STEPS 512
#define BB      256   // batch
#define DD      256   // input dim
#define HH      512   // hidden dim
#define MM      512   // mlp dim
#define AA      64    // action dim

#define NTHR  256
#define GRID  256
#define NGRP  8       // batch groups (32 batches each)
#define GBLK  32      // blocks per group (one per j-tile)
#define BT    32      // batch tile
#define JT    16      // j values per block
#define XHW   768
#define XHP   772     // padded LDS row stride (float4-aligned)

// static device scratch — no reliance on d_ws
__device__ float    g_hT[2][HH][BB];    // h transposed: [j][b]
__device__ float    g_hidT[MM][BB];     // hidden transposed: [m][b]
__device__ unsigned g_cnt[NGRP * 32];   // 128B-padded per group
__device__ unsigned g_gen[NGRP * 32];

__device__ __forceinline__ float sigmoidf_fast(float v) {
    return 1.0f / (1.0f + __expf(-v));
}
__device__ __forceinline__ float dot4(float4 a, float4 b) {
    return a.x * b.x + a.y * b.y + a.z * b.z + a.w * b.w;
}

// 32-block sense barrier; self-resetting (graph-replay safe)
__device__ __forceinline__ void group_barrier(unsigned* cnt, unsigned* gen) {
    __threadfence();
    __syncthreads();
    if (threadIdx.x == 0) {
        unsigned my = __hip_atomic_load(gen, __ATOMIC_ACQUIRE, __HIP_MEMORY_SCOPE_AGENT);
        unsigned prev = __hip_atomic_fetch_add(cnt, 1u, __ATOMIC_ACQ_REL, __HIP_MEMORY_SCOPE_AGENT);
        if (prev == GBLK - 1) {
            __hip_atomic_store(cnt, 0u, __ATOMIC_RELAXED, __HIP_MEMORY_SCOPE_AGENT);
            __hip_atomic_fetch_add(gen, 1u, __ATOMIC_RELEASE, __HIP_MEMORY_SCOPE_AGENT);
        } else {
            while (__hip_atomic_load(gen, __ATOMIC_ACQUIRE, __HIP_MEMORY_SCOPE_AGENT) == my) {}
        }
    }
    __syncthreads();
}

__global__ __launch_bounds__(NTHR, 1) void policy_gru_kernel(
    const float* __restrict__ x,     // [T, B, D]
    const float* __restrict__ W_ih,  // [3H, D]
    const float* __restrict__ W_hh,  // [3H, H]
    const float* __restrict__ b_ih,  // [3H]
    const float* __restrict__ b_hh,  // [3H]
    const float* __restrict__ W1,    // [M, H]
    const float* __restrict__ b1,    // [M]
    const float* __restrict__ W2,    // [A, M]
    const float* __restrict__ b2,    // [A]
    float* __restrict__ out)         // [B, A]
{
    __shared__ float s_xh[BT * XHP];   // 32 x 772 floats = 96.5 KB

    const int tid = threadIdx.x;
    const int blk = blockIdx.x;
    const int g   = blk >> 5;        // batch group 0..7
    const int jt  = blk & 31;        // j tile 0..31
    const int b0  = g * BT;
    const int j0  = jt * JT;
    const int w   = tid >> 6;        // wave 0..3
    const int ln  = tid & 63;
    const int bs  = ln & 31;         // lane batch 0..31
    const int jj  = ln >> 5;         // wave half 0/1
    const int b   = b0 + bs;
    const int jA  = j0 + 4 * w + 2 * jj;  // this lane's two j values
    const int jB  = jA + 1;

    unsigned* cnt = &g_cnt[g * 32];
    unsigned* gen = &g_gen[g * 32];

    // zero-init h0 slice for this block: 16 j x 32 b
    #pragma unroll
    for (int z = 0; z < 2; ++z)
        g_hT[0][j0 + (tid >> 5) + 8 * z][b0 + (tid & 31)] = 0.0f;

    // loop-invariant per-lane state (weights broadcast across 32 b-lanes)
    const float bRA  = b_ih[jA] + b_hh[jA];
    const float bZA  = b_ih[HH + jA] + b_hh[HH + jA];
    const float bXnA = b_ih[2 * HH + jA];
    const float bHnA = b_hh[2 * HH + jA];
    const float bRB  = b_ih[jB] + b_hh[jB];
    const float bZB  = b_ih[HH + jB] + b_hh[HH + jB];
    const float bXnB = b_ih[2 * HH + jB];
    const float bHnB = b_hh[2 * HH + jB];
    const float* __restrict__ wirA = W_ih + (size_t)jA * DD;
    const float* __restrict__ wizA = W_ih + (size_t)(HH + jA) * DD;
    const float* __restrict__ winA = W_ih + (size_t)(2 * HH + jA) * DD;
    const float* __restrict__ whrA = W_hh + (size_t)jA * HH;
    const float* __restrict__ whzA = W_hh + (size_t)(HH + jA) * HH;
    const float* __restrict__ whnA = W_hh + (size_t)(2 * HH + jA) * HH;
    const float* __restrict__ wirB = W_ih + (size_t)jB * DD;
    const float* __restrict__ wizB = W_ih + (size_t)(HH + jB) * DD;
    const float* __restrict__ winB = W_ih + (size_t)(2 * HH + jB) * DD;
    const float* __restrict__ whrB = W_hh + (size_t)jB * HH;
    const float* __restrict__ whzB = W_hh + (size_t)(HH + jB) * HH;
    const float* __restrict__ whnB = W_hh + (size_t)(2 * HH + jB) * HH;

    group_barrier(cnt, gen);

    int cur = 0;
    for (int t = 0; t < T_STEPS; ++t) {
        const float* __restrict__ hT  = &g_hT[cur][0][0];
        float* __restrict__       hTn = &g_hT[cur ^ 1][0][0];

        // ---- stage x[t, b-tile, :] (float4, coalesced: one row per wave) ----
        #pragma unroll
        for (int it = 0; it < 8; ++it) {
            int flat = it * NTHR + tid;
            int row  = flat >> 6;          // 0..31
            int c    = flat & 63;          // float4 index in x row
            float4 v = *(const float4*)(x + ((size_t)t * BB + b0 + row) * DD + 4 * c);
            *(float4*)(&s_xh[row * XHP + 4 * c]) = v;
        }
        // ---- stage h[b-tile, :] from transposed g_hT (coalesced reads) ----
        #pragma unroll 16
        for (int it = 0; it < 64; ++it) {
            int flat = it * NTHR + tid;
            int j    = flat >> 5;          // 0..511
            int bsub = flat & 31;
            s_xh[bsub * XHP + DD + j] = hT[(size_t)j * BB + b0 + bsub];
        }
        __syncthreads();

        // ---- per-lane: 2 j values x (r,z,n), contraction 768 ----
        float aRA = 0.f, aZA = 0.f, aXnA = 0.f, aHnA = 0.f;
        float aRB = 0.f, aZB = 0.f, aXnB = 0.f, aHnB = 0.f;
        const float* vrow = s_xh + bs * XHP;

        #pragma unroll 4
        for (int k = 0; k < DD; k += 4) {
            const float4 v = *(const float4*)(vrow + k);
            aRA  += dot4(v, *(const float4*)(wirA + k));
            aZA  += dot4(v, *(const float4*)(wizA + k));
            aXnA += dot4(v, *(const float4*)(winA + k));
            aRB  += dot4(v, *(const float4*)(wirB + k));
            aZB  += dot4(v, *(const float4*)(wizB + k));
            aXnB += dot4(v, *(const float4*)(winB + k));
        }
        const float* vrh = vrow + DD;
        #pragma unroll 4
        for (int k = 0; k < HH; k += 4) {
            const float4 v = *(const float4*)(vrh + k);
            aRA  += dot4(v, *(const float4*)(whrA + k));
            aZA  += dot4(v, *(const float4*)(whzA + k));
            aHnA += dot4(v, *(const float4*)(whnA + k));
            aRB  += dot4(v, *(const float4*)(whrB + k));
            aZB  += dot4(v, *(const float4*)(whzB + k));
            aHnB += dot4(v, *(const float4*)(whnB + k));
        }

        {
            const float r = sigmoidf_fast(aRA + bRA);
            const float z = sigmoidf_fast(aZA + bZA);
            const float n = tanhf(aXnA + bXnA + r * (aHnA + bHnA));
            const float hprev = vrow[DD + jA];
            hTn[(size_t)jA * BB + b] = (1.0f - z) * n + z * hprev;
        }
        {
            const float r = sigmoidf_fast(aRB + bRB);
            const float z = sigmoidf_fast(aZB + bZB);
            const float n = tanhf(aXnB + bXnB + r * (aHnB + bHnB));
            const float hprev = vrow[DD + jB];
            hTn[(size_t)jB * BB + b] = (1.0f - z) * n + z * hprev;
        }

        group_barrier(cnt, gen);   // also fences LDS reuse across the block
        cur ^= 1;
    }

    const float* __restrict__ hfT = &g_hT[cur][0][0];

    // ---- MLP1: hidden = tanh(h_final @ W1^T + b1); this block: 16 m rows ----
    {
        #pragma unroll 16
        for (int it = 0; it < 64; ++it) {
            int flat = it * NTHR + tid;
            int j    = flat >> 5;
            int bsub = flat & 31;
            s_xh[bsub * XHP + j] = hfT[(size_t)j * BB + b0 + bsub];
        }
        __syncthreads();
        const float* __restrict__ w1A = W1 + (size_t)jA * HH;  // mA == jA
        const float* __restrict__ w1B = W1 + (size_t)jB * HH;
        const float* vrow = s_xh + bs * XHP;
        float accA = 0.f, accB = 0.f;
        #pragma unroll 4
        for (int k = 0; k < HH; k += 4) {
            const float4 v = *(const float4*)(vrow + k);
            accA += dot4(v, *(const float4*)(w1A + k));
            accB += dot4(v, *(const float4*)(w1B + k));
        }
        g_hidT[jA][b] = tanhf(accA + b1[jA]);
        g_hidT[jB][b] = tanhf(accB + b1[jB]);
    }

    group_barrier(cnt, gen);

    // ---- MLP2: out = tanh(hidden @ W2^T + b2); block jt==0 per group ----
    if (jt == 0) {
        #pragma unroll 16
        for (int it = 0; it < 64; ++it) {
            int flat = it * NTHR + tid;
            int m    = flat >> 5;
            int bsub = flat & 31;
            s_xh[bsub * XHP + m] = g_hidT[m][b0 + bsub];
        }
        __syncthreads();
        const int a = tid & 63;
        const float* __restrict__ w2r = W2 + (size_t)a * MM;
        #pragma unroll
        for (int rep = 0; rep < 8; ++rep) {
            const int bsub2 = (tid >> 6) + 4 * rep;
            const float* vrow2 = s_xh + bsub2 * XHP;
            float acc = 0.f;
            #pragma unroll 4
            for (int k = 0; k < MM; k += 4) {
                acc += dot4(*(const float4*)(vrow2 + k), *(const float4*)(w2r + k));
            }
            out[(size_t)(b0 + bsub2) * AA + a] = tanhf(acc + b2[a]);
        }
    }
}

extern "C" void kernel_launch(void* const* d_in, const int* in_sizes, int n_in,
                              void* d_out, int out_size, void* d_ws, size_t ws_size,
                              hipStream_t stream) {
    (void)in_sizes; (void)n_in; (void)out_size; (void)d_ws; (void)ws_size;
    const float* x    = (const float*)d_in[0];
    const float* W_ih = (const float*)d_in[1];
    const float* W_hh = (const float*)d_in[2];
    const float* b_ih = (const float*)d_in[3];
    const float* b_hh = (const float*)d_in[4];
    const float* W1   = (const float*)d_in[5];
    const float* b1   = (const float*)d_in[6];
    const float* W2   = (const float*)d_in[7];
    const float* b2   = (const float*)d_in[8];
    float* out = (float*)d_out;

    policy_gru_kernel<<<dim3(GRID), dim3(NTHR), 0, stream>>>(
        x, W_ih, W_hh, b_ih, b_hh, W1, b1, W2, b2, out);
}

// Round 4
// 27113.196 us; speedup vs baseline: 3.2405x; 1.5189x over previous
//
#include <hip/hip_runtime.h>

#define T_STEPS 512
#define BB      256
#define DD      256
#define HH      512
#define MM      512
#define AA      64

#define NTHR   384      // 6 waves
#define GRID   256
#define NGRP   16       // batch groups of 16
#define GBLK   16       // blocks per group (one per 32-wide j slice)

typedef __attribute__((ext_vector_type(8))) _Float16 halfx8;
typedef __attribute__((ext_vector_type(4))) _Float16 halfx4;
typedef __attribute__((ext_vector_type(4))) float    floatx4;

// fp16 weight copies + hidden-state ping-pong (static: no d_ws dependency)
__device__ __align__(16) _Float16 g_Wih_h[1536 * 256];
__device__ __align__(16) _Float16 g_Whh_h[1536 * 512];
__device__ __align__(16) _Float16 g_W1_h[512 * 512];
__device__ __align__(16) _Float16 g_W2_h[64 * 512];
__device__ __align__(16) _Float16 g_h[2][BB * HH];
__device__ __align__(16) _Float16 g_hid[BB * MM];
__device__ unsigned g_cnt[NGRP * 32];
__device__ unsigned g_gen[NGRP * 32];

__device__ __forceinline__ float sigmoidf_fast(float v) {
    return 1.0f / (1.0f + __expf(-v));
}

// 16-block sense barrier, self-resetting (graph-replay safe)
__device__ __forceinline__ void group_barrier(unsigned* cnt, unsigned* gen) {
    __threadfence();
    __syncthreads();
    if (threadIdx.x == 0) {
        unsigned my = __hip_atomic_load(gen, __ATOMIC_ACQUIRE, __HIP_MEMORY_SCOPE_AGENT);
        unsigned prev = __hip_atomic_fetch_add(cnt, 1u, __ATOMIC_ACQ_REL, __HIP_MEMORY_SCOPE_AGENT);
        if (prev == GBLK - 1) {
            __hip_atomic_store(cnt, 0u, __ATOMIC_RELAXED, __HIP_MEMORY_SCOPE_AGENT);
            __hip_atomic_fetch_add(gen, 1u, __ATOMIC_RELEASE, __HIP_MEMORY_SCOPE_AGENT);
        } else {
            while (__hip_atomic_load(gen, __ATOMIC_ACQUIRE, __HIP_MEMORY_SCOPE_AGENT) == my) {
                __builtin_amdgcn_s_sleep(1);
            }
        }
    }
    __syncthreads();
}

__global__ void convert_weights(const float* __restrict__ Wih, const float* __restrict__ Whh,
                                const float* __restrict__ W1,  const float* __restrict__ W2) {
    int idx = (blockIdx.x * 256 + threadIdx.x) * 4;   // grid covers 1474560 floats exactly
    const float* src; _Float16* dst; int off;
    if (idx < 393216)       { src = Wih; dst = g_Wih_h; off = idx; }
    else if (idx < 1179648) { src = Whh; dst = g_Whh_h; off = idx - 393216; }
    else if (idx < 1441792) { src = W1;  dst = g_W1_h;  off = idx - 1179648; }
    else                    { src = W2;  dst = g_W2_h;  off = idx - 1441792; }
    float4 v = *(const float4*)(src + off);
    halfx4 h = {(_Float16)v.x, (_Float16)v.y, (_Float16)v.z, (_Float16)v.w};
    *(halfx4*)(dst + off) = h;
}

__global__ __launch_bounds__(NTHR, 1) void policy_gru_kernel(
    const float* __restrict__ x,
    const float* __restrict__ b_ih, const float* __restrict__ b_hh,
    const float* __restrict__ b1,   const float* __restrict__ b2,
    float* __restrict__ out)
{
    __shared__ _Float16 s_h[16 * 512];       // swizzled fp16 h tile (16 KB)
    __shared__ _Float16 s_x[2][16 * 256];    // swizzled fp16 x tiles (2x8 KB)
    __shared__ float    s_pre[16 * 132];     // gate pre-activations (8.4 KB)
    __shared__ float    s_bias[4 * 32];      // br, bz, bxn, bhn for this j-slice

    const int tid = threadIdx.x;
    const int blk = blockIdx.x;
    const int g   = (blk & 7) + 8 * (blk >> 7);   // group 0..15 (same-XCD members)
    const int mi  = (blk >> 3) & 15;              // member 0..15
    const int b0  = g << 4;
    const int j0  = mi << 5;
    const int w   = tid >> 6;                     // wave 0..5
    const int l   = tid & 63;

    char* s_h_b  = (char*)s_h;
    char* s_x0_b = (char*)s_x[0];
    char* s_x1_b = (char*)s_x[1];

    unsigned* cnt = &g_cnt[g * 32];
    unsigned* gen = &g_gen[g * 32];

    // zero h0 slice [16b x 32j]
    for (int p = tid; p < 512; p += NTHR) {
        int b = p >> 5, jj = p & 31;
        g_h[0][(b0 + b) * HH + j0 + jj] = (_Float16)0.0f;
    }
    // biases for this j-slice
    if (tid < 32) {
        s_bias[tid]      = b_ih[j0 + tid] + b_hh[j0 + tid];                 // r
        s_bias[32 + tid] = b_ih[HH + j0 + tid] + b_hh[HH + j0 + tid];       // z
        s_bias[64 + tid] = b_ih[2 * HH + j0 + tid];                         // xn
        s_bias[96 + tid] = b_hh[2 * HH + j0 + tid];                         // hn
    }

    // persistent W fragments: waves 0-3 hold W_hh (kiters 4w..4w+3 of 16),
    // waves 4-5 hold W_ih (kiters 4(w-4)..+3 of 8). 6 col-tiles: r,r,z,z,n,n.
    halfx8 bW[6][4];
    #pragma unroll
    for (int c = 0; c < 6; ++c) {
        int grow = ((c >> 1) << 9) + j0 + ((c & 1) << 4) + (l & 15);
        #pragma unroll
        for (int i = 0; i < 4; ++i) {
            if (w < 4)
                bW[c][i] = *(const halfx8*)(g_Whh_h + (size_t)grow * 512 + (4 * w + i) * 32 + ((l >> 4) << 3));
            else
                bW[c][i] = *(const halfx8*)(g_Wih_h + (size_t)grow * 256 + (4 * (w - 4) + i) * 32 + ((l >> 4) << 3));
        }
    }

    group_barrier(cnt, gen);

    // stage x[0] into s_x[0]
    for (int r = 0; r < 3; ++r) {
        int flat = r * NTHR + tid;
        if (flat < 1024) {
            int b = flat >> 6, c4 = flat & 63;
            float4 v = *(const float4*)(x + ((size_t)0 * BB + b0 + b) * DD + c4 * 4);
            halfx4 h = {(_Float16)v.x, (_Float16)v.y, (_Float16)v.z, (_Float16)v.w};
            int off = (b * 512 + c4 * 8) ^ ((b & 7) << 4);
            *(halfx4*)(s_x0_b + off) = h;
        }
    }

    int cur = 0;
    for (int t = 0; t < T_STEPS; ++t) {
        const int nxt = cur ^ 1;
        // issue x[t+1] loads early (latency hidden under staging/MFMA)
        float4 xv[3];
        const bool havex = (t + 1 < T_STEPS);
        if (havex) {
            #pragma unroll
            for (int r = 0; r < 3; ++r) {
                int flat = r * NTHR + tid;
                if (flat < 1024)
                    xv[r] = *(const float4*)(x + ((size_t)(t + 1) * BB + b0 + (flat >> 6)) * DD + (flat & 63) * 4);
            }
        }
        // stage h tile (fp16, XOR-swizzled rows)
        for (int r = 0; r < 3; ++r) {
            int flat = r * NTHR + tid;
            if (flat < 1024) {
                int b = flat >> 6, c = flat & 63;
                halfx8 v = *(const halfx8*)(g_h[cur] + (size_t)(b0 + b) * HH + c * 8);
                int off = (b * 1024 + c * 16) ^ ((b & 7) << 4);
                *(halfx8*)(s_h_b + off) = v;
            }
        }
        // zero s_pre
        for (int r = 0; r < 6; ++r) {
            int idx = r * NTHR + tid;
            if (idx < 16 * 132) s_pre[idx] = 0.0f;
        }
        __syncthreads();

        // MFMA: k-split partial sums
        floatx4 acc[6] = {};
        char* sxb = (cur == 0) ? s_x0_b : s_x1_b;
        #pragma unroll
        for (int i = 0; i < 4; ++i) {
            halfx8 a;
            if (w < 4) {
                int kk = 4 * w + i;
                int off = ((l & 15) * 1024 + kk * 64 + ((l >> 4) << 4)) ^ ((l & 7) << 4);
                a = *(halfx8*)(s_h_b + off);
            } else {
                int xk = 4 * (w - 4) + i;
                int off = ((l & 15) * 512 + xk * 64 + ((l >> 4) << 4)) ^ ((l & 7) << 4);
                a = *(halfx8*)(sxb + off);
            }
            #pragma unroll
            for (int c = 0; c < 6; ++c)
                acc[c] = __builtin_amdgcn_mfma_f32_16x16x32_f16(a, bW[c][i], acc[c], 0, 0, 0);
        }
        // merge partials: r cols 0-31, z 32-63, n(h) 64-95, n(x) 96-127
        #pragma unroll
        for (int c = 0; c < 6; ++c) {
            int colb = (c < 4) ? (c << 4) : (64 + ((c & 1) << 4) + (w >= 4 ? 32 : 0));
            int col = colb + (l & 15);
            #pragma unroll
            for (int q = 0; q < 4; ++q) {
                int b = ((l >> 4) << 2) + q;
                atomicAdd(&s_pre[b * 132 + col], acc[c][q]);
            }
        }
        // write x[t+1] into the other x buffer
        if (havex) {
            #pragma unroll
            for (int r = 0; r < 3; ++r) {
                int flat = r * NTHR + tid;
                if (flat < 1024) {
                    int b = flat >> 6, c4 = flat & 63;
                    halfx4 h = {(_Float16)xv[r].x, (_Float16)xv[r].y, (_Float16)xv[r].z, (_Float16)xv[r].w};
                    int off = (b * 512 + c4 * 8) ^ ((b & 7) << 4);
                    *(halfx4*)(((nxt == 0) ? s_x0_b : s_x1_b) + off) = h;
                }
            }
        }
        __syncthreads();

        // combine gates -> h_new
        for (int p = tid; p < 512; p += NTHR) {
            int b = p >> 5, jj = p & 31;
            const float* pre = s_pre + b * 132;
            float rr = sigmoidf_fast(pre[jj] + s_bias[jj]);
            float zz = sigmoidf_fast(pre[32 + jj] + s_bias[32 + jj]);
            float nn = tanhf(pre[96 + jj] + s_bias[64 + jj] + rr * (pre[64 + jj] + s_bias[96 + jj]));
            int hoff = ((b * 1024 + (j0 + jj) * 2)) ^ ((b & 7) << 4);
            float hp = (float)(*(_Float16*)(s_h_b + hoff));
            float hnew = (1.0f - zz) * nn + zz * hp;
            g_h[nxt][(size_t)(b0 + b) * HH + j0 + jj] = (_Float16)hnew;
        }

        group_barrier(cnt, gen);
        cur = nxt;
    }
    // cur == 0 here; h_final in g_h[0]

    // ---- MLP1: hidden = tanh(h_final @ W1^T + b1); block does m-slice [j0, j0+32) ----
    halfx8 w1f[2][4];
    if (w < 4) {
        #pragma unroll
        for (int c = 0; c < 2; ++c) {
            int grow = j0 + (c << 4) + (l & 15);
            #pragma unroll
            for (int i = 0; i < 4; ++i)
                w1f[c][i] = *(const halfx8*)(g_W1_h + (size_t)grow * 512 + (4 * w + i) * 32 + ((l >> 4) << 3));
        }
    }
    for (int r = 0; r < 3; ++r) {
        int flat = r * NTHR + tid;
        if (flat < 1024) {
            int b = flat >> 6, c = flat & 63;
            halfx8 v = *(const halfx8*)(g_h[0] + (size_t)(b0 + b) * HH + c * 8);
            int off = (b * 1024 + c * 16) ^ ((b & 7) << 4);
            *(halfx8*)(s_h_b + off) = v;
        }
    }
    for (int r = 0; r < 6; ++r) {
        int idx = r * NTHR + tid;
        if (idx < 16 * 132) s_pre[idx] = 0.0f;
    }
    __syncthreads();
    if (w < 4) {
        floatx4 acc2[2] = {};
        #pragma unroll
        for (int i = 0; i < 4; ++i) {
            int kk = 4 * w + i;
            int off = ((l & 15) * 1024 + kk * 64 + ((l >> 4) << 4)) ^ ((l & 7) << 4);
            halfx8 a = *(halfx8*)(s_h_b + off);
            #pragma unroll
            for (int c = 0; c < 2; ++c)
                acc2[c] = __builtin_amdgcn_mfma_f32_16x16x32_f16(a, w1f[c][i], acc2[c], 0, 0, 0);
        }
        #pragma unroll
        for (int c = 0; c < 2; ++c) {
            int col = (c << 4) + (l & 15);
            #pragma unroll
            for (int q = 0; q < 4; ++q)
                atomicAdd(&s_pre[(((l >> 4) << 2) + q) * 132 + col], acc2[c][q]);
        }
    }
    __syncthreads();
    for (int p = tid; p < 512; p += NTHR) {
        int b = p >> 5, ml = p & 31;
        float v = tanhf(s_pre[b * 132 + ml] + b1[j0 + ml]);
        g_hid[(size_t)(b0 + b) * MM + j0 + ml] = (_Float16)v;
    }
    group_barrier(cnt, gen);

    // ---- MLP2: out = tanh(hidden @ W2^T + b2); member 0 of each group ----
    if (mi == 0) {
        halfx8 w2f[4][4];
        if (w < 4) {
            #pragma unroll
            for (int c = 0; c < 4; ++c) {
                int grow = (c << 4) + (l & 15);
                #pragma unroll
                for (int i = 0; i < 4; ++i)
                    w2f[c][i] = *(const halfx8*)(g_W2_h + (size_t)grow * 512 + (4 * w + i) * 32 + ((l >> 4) << 3));
            }
        }
        for (int r = 0; r < 3; ++r) {
            int flat = r * NTHR + tid;
            if (flat < 1024) {
                int b = flat >> 6, c = flat & 63;
                halfx8 v = *(const halfx8*)(g_hid + (size_t)(b0 + b) * MM + c * 8);
                int off = (b * 1024 + c * 16) ^ ((b & 7) << 4);
                *(halfx8*)(s_h_b + off) = v;
            }
        }
        for (int r = 0; r < 6; ++r) {
            int idx = r * NTHR + tid;
            if (idx < 16 * 132) s_pre[idx] = 0.0f;
        }
        __syncthreads();
        if (w < 4) {
            floatx4 acc4[4] = {};
            #pragma unroll
            for (int i = 0; i < 4; ++i) {
                int kk = 4 * w + i;
                int off = ((l & 15) * 1024 + kk * 64 + ((l >> 4) << 4)) ^ ((l & 7) << 4);
                halfx8 a = *(halfx8*)(s_h_b + off);
                #pragma unroll
                for (int c = 0; c < 4; ++c)
                    acc4[c] = __builtin_amdgcn_mfma_f32_16x16x32_f16(a, w2f[c][i], acc4[c], 0, 0, 0);
            }
            #pragma unroll
            for (int c = 0; c < 4; ++c) {
                int col = (c << 4) + (l & 15);
                #pragma unroll
                for (int q = 0; q < 4; ++q)
                    atomicAdd(&s_pre[(((l >> 4) << 2) + q) * 132 + col], acc4[c][q]);
            }
        }
        __syncthreads();
        for (int p = tid; p < 1024; p += NTHR) {
            int b = p >> 6, a = p & 63;
            out[(size_t)(b0 + b) * AA + a] = tanhf(s_pre[b * 132 + a] + b2[a]);
        }
    }
}

extern "C" void kernel_launch(void* const* d_in, const int* in_sizes, int n_in,
                              void* d_out, int out_size, void* d_ws, size_t ws_size,
                              hipStream_t stream) {
    (void)in_sizes; (void)n_in; (void)out_size; (void)d_ws; (void)ws_size;
    const float* x    = (const float*)d_in[0];
    const float* W_ih = (const float*)d_in[1];
    const float* W_hh = (const float*)d_in[2];
    const float* b_ih = (const float*)d_in[3];
    const float* b_hh = (const float*)d_in[4];
    const float* W1   = (const float*)d_in[5];
    const float* b1   = (const float*)d_in[6];
    const float* W2   = (const float*)d_in[7];
    const float* b2   = (const float*)d_in[8];
    float* out = (float*)d_out;

    convert_weights<<<dim3(1440), dim3(256), 0, stream>>>(W_ih, W_hh, W1, W2);
    policy_gru_kernel<<<dim3(GRID), dim3(NTHR), 0, stream>>>(
        x, b_ih, b_hh, b1, b2, out);
}

// Round 5
// 8306.753 us; speedup vs baseline: 10.5771x; 3.2640x over previous
//
#include <hip/hip_runtime.h>

#define T_STEPS 512
#define BB      256
#define DD      256
#define HH      512
#define MM      512
#define AA      64

#define NTHR   384      // 6 waves
#define GRID   256
#define NGRP   16       // batch groups of 16
#define GBLK   16       // blocks per group (one per 32-wide j slice)

typedef __attribute__((ext_vector_type(8))) _Float16 halfx8;
typedef __attribute__((ext_vector_type(4))) _Float16 halfx4;
typedef __attribute__((ext_vector_type(4))) float    floatx4;

// fp16 weight copies + hidden-state ping-pong (static: no d_ws dependency)
__device__ __align__(16) _Float16 g_Wih_h[1536 * 256];
__device__ __align__(16) _Float16 g_Whh_h[1536 * 512];
__device__ __align__(16) _Float16 g_W1_h[512 * 512];
__device__ __align__(16) _Float16 g_W2_h[64 * 512];
__device__ __align__(16) _Float16 g_h[2][BB * HH];
__device__ __align__(16) _Float16 g_hid[BB * MM];
__device__ unsigned long long g_bar[NGRP * 16];   // packed [gen:32|cnt:32], 128B apart

__device__ __forceinline__ float sigmoidf_fast(float v) {
    return 1.0f / (1.0f + __expf(-v));
}

// device-coherent (MALL-point) relaxed accessors — no L2 flush/inv
__device__ __forceinline__ unsigned long long ld_u64_sc(const _Float16* p) {
    return __hip_atomic_load((const unsigned long long*)p, __ATOMIC_RELAXED, __HIP_MEMORY_SCOPE_AGENT);
}
__device__ __forceinline__ void st_u64_sc(_Float16* p, unsigned long long v) {
    __hip_atomic_store((unsigned long long*)p, v, __ATOMIC_RELAXED, __HIP_MEMORY_SCOPE_AGENT);
}
__device__ __forceinline__ void st_u32_sc(_Float16* p, unsigned v) {
    __hip_atomic_store((unsigned*)p, v, __ATOMIC_RELAXED, __HIP_MEMORY_SCOPE_AGENT);
}

// fence-free 16-block barrier: per-wave vmcnt drain publishes data, then one
// relaxed fetch_add on a single packed word (coherence-ordered; self-resetting)
__device__ __forceinline__ void group_barrier(unsigned long long* bar) {
    asm volatile("s_waitcnt vmcnt(0) lgkmcnt(0)" ::: "memory");
    __syncthreads();
    if (threadIdx.x == 0) {
        unsigned long long old =
            __hip_atomic_fetch_add(bar, 1ull, __ATOMIC_RELAXED, __HIP_MEMORY_SCOPE_AGENT);
        unsigned my = (unsigned)(old >> 32);
        if ((old & 0xffffffffull) == (unsigned long long)(GBLK - 1)) {
            __hip_atomic_fetch_add(bar, (1ull << 32) - (unsigned long long)GBLK,
                                   __ATOMIC_RELAXED, __HIP_MEMORY_SCOPE_AGENT);
        } else {
            while ((unsigned)(__hip_atomic_load(bar, __ATOMIC_RELAXED,
                                                __HIP_MEMORY_SCOPE_AGENT) >> 32) == my) {}
        }
    }
    __syncthreads();
}

__global__ void convert_weights(const float* __restrict__ Wih, const float* __restrict__ Whh,
                                const float* __restrict__ W1,  const float* __restrict__ W2) {
    int idx = (blockIdx.x * 256 + threadIdx.x) * 4;   // grid covers 1474560 floats exactly
    const float* src; _Float16* dst; int off;
    if (idx < 393216)       { src = Wih; dst = g_Wih_h; off = idx; }
    else if (idx < 1179648) { src = Whh; dst = g_Whh_h; off = idx - 393216; }
    else if (idx < 1441792) { src = W1;  dst = g_W1_h;  off = idx - 1179648; }
    else                    { src = W2;  dst = g_W2_h;  off = idx - 1441792; }
    float4 v = *(const float4*)(src + off);
    halfx4 h = {(_Float16)v.x, (_Float16)v.y, (_Float16)v.z, (_Float16)v.w};
    *(halfx4*)(dst + off) = h;
}

__global__ __launch_bounds__(NTHR, 1) void policy_gru_kernel(
    const float* __restrict__ x,
    const float* __restrict__ b_ih, const float* __restrict__ b_hh,
    const float* __restrict__ b1,   const float* __restrict__ b2,
    float* __restrict__ out)
{
    __shared__ _Float16 s_h[16 * 512];       // swizzled fp16 h tile (16 KB)
    __shared__ _Float16 s_x[2][16 * 256];    // swizzled fp16 x tiles (2x8 KB)
    __shared__ float    s_pre[16 * 132];     // gate pre-activations (8.4 KB)
    __shared__ float    s_bias[4 * 32];

    const int tid = threadIdx.x;
    const int blk = blockIdx.x;
    const int g   = (blk & 7) + 8 * (blk >> 7);   // group 0..15
    const int mi  = (blk >> 3) & 15;              // member 0..15
    const int b0  = g << 4;
    const int j0  = mi << 5;
    const int w   = tid >> 6;
    const int l   = tid & 63;

    char* s_h_b  = (char*)s_h;
    char* s_x0_b = (char*)s_x[0];
    char* s_x1_b = (char*)s_x[1];

    unsigned long long* bar = &g_bar[g * 16];

    // zero h0 slice [16b x 32j] via device-coherent stores (8 ull words per row)
    if (tid < 128) {
        int b = tid >> 3, c = tid & 7;
        st_u64_sc(&g_h[0][(size_t)(b0 + b) * HH + j0 + c * 4], 0ull);
    }
    if (tid < 32) {
        s_bias[tid]      = b_ih[j0 + tid] + b_hh[j0 + tid];
        s_bias[32 + tid] = b_ih[HH + j0 + tid] + b_hh[HH + j0 + tid];
        s_bias[64 + tid] = b_ih[2 * HH + j0 + tid];
        s_bias[96 + tid] = b_hh[2 * HH + j0 + tid];
    }

    // persistent W fragments: waves 0-3 hold W_hh, waves 4-5 hold W_ih
    halfx8 bW[6][4];
    #pragma unroll
    for (int c = 0; c < 6; ++c) {
        int grow = ((c >> 1) << 9) + j0 + ((c & 1) << 4) + (l & 15);
        #pragma unroll
        for (int i = 0; i < 4; ++i) {
            if (w < 4)
                bW[c][i] = *(const halfx8*)(g_Whh_h + (size_t)grow * 512 + (4 * w + i) * 32 + ((l >> 4) << 3));
            else
                bW[c][i] = *(const halfx8*)(g_Wih_h + (size_t)grow * 256 + (4 * (w - 4) + i) * 32 + ((l >> 4) << 3));
        }
    }

    group_barrier(bar);

    // stage x[0] into s_x[0]
    for (int r = 0; r < 3; ++r) {
        int flat = r * NTHR + tid;
        if (flat < 1024) {
            int b = flat >> 6, c4 = flat & 63;
            float4 v = *(const float4*)(x + ((size_t)0 * BB + b0 + b) * DD + c4 * 4);
            halfx4 h = {(_Float16)v.x, (_Float16)v.y, (_Float16)v.z, (_Float16)v.w};
            int off = (b * 512 + c4 * 8) ^ ((b & 7) << 4);
            *(halfx4*)(s_x0_b + off) = h;
        }
    }

    int cur = 0;
    for (int t = 0; t < T_STEPS; ++t) {
        const int nxt = cur ^ 1;
        // issue x[t+1] loads early
        float4 xv[3];
        const bool havex = (t + 1 < T_STEPS);
        if (havex) {
            #pragma unroll
            for (int r = 0; r < 3; ++r) {
                int flat = r * NTHR + tid;
                if (flat < 1024)
                    xv[r] = *(const float4*)(x + ((size_t)(t + 1) * BB + b0 + (flat >> 6)) * DD + (flat & 63) * 4);
            }
        }
        // stage h tile via device-coherent 8B loads (fp16, XOR-swizzled)
        #pragma unroll
        for (int r = 0; r < 6; ++r) {
            int flat = r * NTHR + tid;
            if (flat < 2048) {
                int b = flat >> 7, c = flat & 127;        // c: 8B unit (4 halves)
                unsigned long long v = ld_u64_sc(&g_h[cur][(size_t)(b0 + b) * HH + c * 4]);
                int off = (b * 1024 + c * 8) ^ ((b & 7) << 4);
                *(unsigned long long*)(s_h_b + off) = v;
            }
        }
        // zero s_pre
        for (int r = 0; r < 6; ++r) {
            int idx = r * NTHR + tid;
            if (idx < 16 * 132) s_pre[idx] = 0.0f;
        }
        __syncthreads();

        // MFMA: k-split partial sums
        floatx4 acc[6] = {};
        char* sxb = (cur == 0) ? s_x0_b : s_x1_b;
        #pragma unroll
        for (int i = 0; i < 4; ++i) {
            halfx8 a;
            if (w < 4) {
                int kk = 4 * w + i;
                int off = ((l & 15) * 1024 + kk * 64 + ((l >> 4) << 4)) ^ ((l & 7) << 4);
                a = *(halfx8*)(s_h_b + off);
            } else {
                int xk = 4 * (w - 4) + i;
                int off = ((l & 15) * 512 + xk * 64 + ((l >> 4) << 4)) ^ ((l & 7) << 4);
                a = *(halfx8*)(sxb + off);
            }
            #pragma unroll
            for (int c = 0; c < 6; ++c)
                acc[c] = __builtin_amdgcn_mfma_f32_16x16x32_f16(a, bW[c][i], acc[c], 0, 0, 0);
        }
        // merge partials into s_pre
        #pragma unroll
        for (int c = 0; c < 6; ++c) {
            int colb = (c < 4) ? (c << 4) : (64 + ((c & 1) << 4) + (w >= 4 ? 32 : 0));
            int col = colb + (l & 15);
            #pragma unroll
            for (int q = 0; q < 4; ++q) {
                int b = ((l >> 4) << 2) + q;
                atomicAdd(&s_pre[b * 132 + col], acc[c][q]);
            }
        }
        // write x[t+1] into the other x buffer
        if (havex) {
            #pragma unroll
            for (int r = 0; r < 3; ++r) {
                int flat = r * NTHR + tid;
                if (flat < 1024) {
                    int b = flat >> 6, c4 = flat & 63;
                    halfx4 h = {(_Float16)xv[r].x, (_Float16)xv[r].y, (_Float16)xv[r].z, (_Float16)xv[r].w};
                    int off = (b * 512 + c4 * 8) ^ ((b & 7) << 4);
                    *(halfx4*)(((nxt == 0) ? s_x0_b : s_x1_b) + off) = h;
                }
            }
        }
        __syncthreads();

        // combine gates -> h_new (pack 2 j per 4B coherent store)
        for (int p = tid; p < 256; p += NTHR) {
            int b = p >> 4, jj = (p & 15) * 2;
            const float* pre = s_pre + b * 132;
            int hoff = (b * 1024 + (j0 + jj) * 2) ^ ((b & 7) << 4);
            unsigned hp2 = *(unsigned*)(s_h_b + hoff);
            union { unsigned u; _Float16 h[2]; } hpu, po;
            hpu.u = hp2;
            #pragma unroll
            for (int e = 0; e < 2; ++e) {
                int jje = jj + e;
                float rr = sigmoidf_fast(pre[jje] + s_bias[jje]);
                float zz = sigmoidf_fast(pre[32 + jje] + s_bias[32 + jje]);
                float nn = tanhf(pre[96 + jje] + s_bias[64 + jje] + rr * (pre[64 + jje] + s_bias[96 + jje]));
                float hp = (float)hpu.h[e];
                po.h[e] = (_Float16)((1.0f - zz) * nn + zz * hp);
            }
            st_u32_sc(&g_h[nxt][(size_t)(b0 + b) * HH + j0 + jj], po.u);
        }

        group_barrier(bar);
        cur = nxt;
    }
    // h_final in g_h[cur] (cur == 0)

    // ---- MLP1: hidden = tanh(h_final @ W1^T + b1) ----
    halfx8 w1f[2][4];
    if (w < 4) {
        #pragma unroll
        for (int c = 0; c < 2; ++c) {
            int grow = j0 + (c << 4) + (l & 15);
            #pragma unroll
            for (int i = 0; i < 4; ++i)
                w1f[c][i] = *(const halfx8*)(g_W1_h + (size_t)grow * 512 + (4 * w + i) * 32 + ((l >> 4) << 3));
        }
    }
    #pragma unroll
    for (int r = 0; r < 6; ++r) {
        int flat = r * NTHR + tid;
        if (flat < 2048) {
            int b = flat >> 7, c = flat & 127;
            unsigned long long v = ld_u64_sc(&g_h[cur][(size_t)(b0 + b) * HH + c * 4]);
            int off = (b * 1024 + c * 8) ^ ((b & 7) << 4);
            *(unsigned long long*)(s_h_b + off) = v;
        }
    }
    for (int r = 0; r < 6; ++r) {
        int idx = r * NTHR + tid;
        if (idx < 16 * 132) s_pre[idx] = 0.0f;
    }
    __syncthreads();
    if (w < 4) {
        floatx4 acc2[2] = {};
        #pragma unroll
        for (int i = 0; i < 4; ++i) {
            int kk = 4 * w + i;
            int off = ((l & 15) * 1024 + kk * 64 + ((l >> 4) << 4)) ^ ((l & 7) << 4);
            halfx8 a = *(halfx8*)(s_h_b + off);
            #pragma unroll
            for (int c = 0; c < 2; ++c)
                acc2[c] = __builtin_amdgcn_mfma_f32_16x16x32_f16(a, w1f[c][i], acc2[c], 0, 0, 0);
        }
        #pragma unroll
        for (int c = 0; c < 2; ++c) {
            int col = (c << 4) + (l & 15);
            #pragma unroll
            for (int q = 0; q < 4; ++q)
                atomicAdd(&s_pre[(((l >> 4) << 2) + q) * 132 + col], acc2[c][q]);
        }
    }
    __syncthreads();
    for (int p = tid; p < 256; p += NTHR) {
        int b = p >> 4, ml = (p & 15) * 2;
        union { unsigned u; _Float16 h[2]; } po;
        po.h[0] = (_Float16)tanhf(s_pre[b * 132 + ml] + b1[j0 + ml]);
        po.h[1] = (_Float16)tanhf(s_pre[b * 132 + ml + 1] + b1[j0 + ml + 1]);
        st_u32_sc(&g_hid[(size_t)(b0 + b) * MM + j0 + ml], po.u);
    }
    group_barrier(bar);

    // ---- MLP2: out = tanh(hidden @ W2^T + b2); member 0 of each group ----
    if (mi == 0) {
        halfx8 w2f[4][4];
        if (w < 4) {
            #pragma unroll
            for (int c = 0; c < 4; ++c) {
                int grow = (c << 4) + (l & 15);
                #pragma unroll
                for (int i = 0; i < 4; ++i)
                    w2f[c][i] = *(const halfx8*)(g_W2_h + (size_t)grow * 512 + (4 * w + i) * 32 + ((l >> 4) << 3));
            }
        }
        #pragma unroll
        for (int r = 0; r < 6; ++r) {
            int flat = r * NTHR + tid;
            if (flat < 2048) {
                int b = flat >> 7, c = flat & 127;
                unsigned long long v = ld_u64_sc(&g_hid[(size_t)(b0 + b) * MM + c * 4]);
                int off = (b * 1024 + c * 8) ^ ((b & 7) << 4);
                *(unsigned long long*)(s_h_b + off) = v;
            }
        }
        for (int r = 0; r < 6; ++r) {
            int idx = r * NTHR + tid;
            if (idx < 16 * 132) s_pre[idx] = 0.0f;
        }
        __syncthreads();
        if (w < 4) {
            floatx4 acc4[4] = {};
            #pragma unroll
            for (int i = 0; i < 4; ++i) {
                int kk = 4 * w + i;
                int off = ((l & 15) * 1024 + kk * 64 + ((l >> 4) << 4)) ^ ((l & 7) << 4);
                halfx8 a = *(halfx8*)(s_h_b + off);
                #pragma unroll
                for (int c = 0; c < 4; ++c)
                    acc4[c] = __builtin_amdgcn_mfma_f32_16x16x32_f16(a, w2f[c][i], acc4[c], 0, 0, 0);
            }
            #pragma unroll
            for (int c = 0; c < 4; ++c) {
                int col = (c << 4) + (l & 15);
                #pragma unroll
                for (int q = 0; q < 4; ++q)
                    atomicAdd(&s_pre[(((l >> 4) << 2) + q) * 132 + col], acc4[c][q]);
            }
        }
        __syncthreads();
        for (int p = tid; p < 1024; p += NTHR) {
            int b = p >> 6, a = p & 63;
            out[(size_t)(b0 + b) * AA + a] = tanhf(s_pre[b * 132 + a] + b2[a]);
        }
    }
}

extern "C" void kernel_launch(void* const* d_in, const int* in_sizes, int n_in,
                              void* d_out, int out_size, void* d_ws, size_t ws_size,
                              hipStream_t stream) {
    (void)in_sizes; (void)n_in; (void)out_size; (void)d_ws; (void)ws_size;
    const float* x    = (const float*)d_in[0];
    const float* W_ih = (const float*)d_in[1];
    const float* W_hh = (const float*)d_in[2];
    const float* b_ih = (const float*)d_in[3];
    const float* b_hh = (const float*)d_in[4];
    const float* W1   = (const float*)d_in[5];
    const float* b1   = (const float*)d_in[6];
    const float* W2   = (const float*)d_in[7];
    const float* b2   = (const float*)d_in[8];
    float* out = (float*)d_out;

    convert_weights<<<dim3(1440), dim3(256), 0, stream>>>(W_ih, W_hh, W1, W2);
    policy_gru_kernel<<<dim3(GRID), dim3(NTHR), 0, stream>>>(
        x, b_ih, b_hh, b1, b2, out);
}